// Round 6
// baseline (312.526 us; speedup 1.0000x reference)
//
#include <hip/hip_runtime.h>
#include <math.h>

namespace {

typedef __attribute__((ext_vector_type(8))) short short8;
typedef __attribute__((ext_vector_type(4))) float f32x4;

constexpr int B  = 2;
constexpr int C  = 256;
constexpr int NH = 8;
constexpr int L  = 4;
constexpr int P  = 4;
constexpr int D  = 32;
constexpr int LV = 13294;
constexpr int LQ = 13294;
constexpr int M  = B * LQ;      // 26588 rows for all GEMMs

constexpr int SZ[4]    = {100, 50, 25, 13};
constexpr int START[4] = {0, 10000, 12500, 13125};

constexpr int CVT_BLOCKS = (2 * M) / 4;   // 13294 (exact: 4 rows/block)

__device__ inline short bf16r(float f) {    // RTNE f32 -> bf16
  unsigned u = __float_as_uint(f);
  u += 0x7fff + ((u >> 16) & 1);
  return (short)(u >> 16);
}

__device__ inline void load_a_bf16(const unsigned short* __restrict__ arow, short8 a[8]) {
#pragma unroll
  for (int s = 0; s < 8; ++s)
    a[s] = *reinterpret_cast<const short8*>(arow + s * 32);
}

// ---------------------------------------------------------------------------
// k_pre: fused input convert (query/value f32 -> bf16 [m][256]) + weight
// transpose/convert (W[k][n] -> Bt[n][k] bf16).
// Blocks [0, CVT_BLOCKS): cvt, 4 rows per 256-thread block.
// Blocks [CVT_BLOCKS, CVT_BLOCKS+224): weight prep, 32x32 tiles.
// ---------------------------------------------------------------------------
__global__ __launch_bounds__(256) void k_pre(
    const float* __restrict__ query, const float* __restrict__ value,
    const float* __restrict__ Wv, const float* __restrict__ Woff,
    const float* __restrict__ Wattn, const float* __restrict__ Wo,
    unsigned short* __restrict__ qbf, unsigned short* __restrict__ vbf,
    unsigned short* __restrict__ Btv, unsigned short* __restrict__ Btoa,
    unsigned short* __restrict__ Bto) {
  __shared__ float tile[32][33];
  if (blockIdx.x < CVT_BLOCKS) {
    const int gid = blockIdx.x * 256 + threadIdx.x;
    const int rid = gid >> 6;              // row id over 2*M
    if (rid >= 2 * M) return;
    const int c4 = (gid & 63) * 4;
    const int tensor = (rid >= M) ? 1 : 0;
    const int m = tensor ? rid - M : rid;
    const int b = m / LQ, i = m - b * LQ;
    const float* src = (tensor ? value : query) + ((size_t)(i * B + b)) * C + c4;
    const f32x4 f = *reinterpret_cast<const f32x4*>(src);
    unsigned short* dst = (tensor ? vbf : qbf) + (size_t)m * C + c4;
    uint2 o;
    o.x = (unsigned)(unsigned short)bf16r(f[0]) | ((unsigned)(unsigned short)bf16r(f[1]) << 16);
    o.y = (unsigned)(unsigned short)bf16r(f[2]) | ((unsigned)(unsigned short)bf16r(f[3]) << 16);
    *reinterpret_cast<uint2*>(dst) = o;
    return;
  }
  const int blk = blockIdx.x - CVT_BLOCKS;
  const float* src; unsigned short* dst; int N, local;
  if (blk < 64)       { src = Wv;    dst = Btv;              N = 256; local = blk; }
  else if (blk < 128) { src = Woff;  dst = Btoa;             N = 256; local = blk - 64; }
  else if (blk < 160) { src = Wattn; dst = Btoa + 256 * 256; N = 128; local = blk - 128; }
  else                { src = Wo;    dst = Bto;              N = 256; local = blk - 160; }
  const int ntiles = N >> 5;
  const int kt = local / ntiles, nt = local - kt * ntiles;
  const int k0 = kt << 5, n0 = nt << 5;
  const int tx = threadIdx.x & 31, ty = threadIdx.x >> 5;
#pragma unroll
  for (int r = 0; r < 4; ++r) {
    const int kk = ty + r * 8;
    tile[kk][tx] = src[(size_t)(k0 + kk) * N + n0 + tx];
  }
  __syncthreads();
#pragma unroll
  for (int r = 0; r < 4; ++r) {
    const int nn = ty + r * 8;
    dst[(size_t)(n0 + nn) * 256 + k0 + tx] = (unsigned short)bf16r(tile[tx][nn]);
  }
}

// ---------------------------------------------------------------------------
// k_gemm12: merged GEMM 1 (val-proj) + GEMM 2 (offsets+attn).
// One 64-thread wave per block; wave = 64 M-rows (4 chains) x 64 N-cols.
// blockIdx.y: 0..3 -> val-proj N-split; 4..9 -> offattn N-split.
// 4 MFMA chains per B fragment -> B demand ~50 B/cyc/CU (under L2 ceiling).
// ---------------------------------------------------------------------------
__global__ __launch_bounds__(64) void k_gemm12(
    const unsigned short* __restrict__ qbf, const unsigned short* __restrict__ vbf,
    const float* __restrict__ rp,
    const unsigned short* __restrict__ Btv, const unsigned short* __restrict__ Btoa,
    const float* __restrict__ bv, const float* __restrict__ boff,
    const float* __restrict__ battn,
    unsigned short* __restrict__ val, float* __restrict__ loc,
    float* __restrict__ attn) {
  const int lane = threadIdx.x, quad = lane >> 4, lo = lane & 15;
  const int y = blockIdx.y;
  const bool isval = (y < 4);
  const unsigned short* Abf = isval ? vbf : qbf;
  const unsigned short* Bt  = isval ? Btv : Btoa;
  const int tbase = isval ? y * 4 : (y - 4) * 4;
  const int m0 = blockIdx.x * 64;

  short8 a[4][8];
#pragma unroll
  for (int c = 0; c < 4; ++c) {
    const int mr = min(m0 + c * 16 + lo, M - 1);
    load_a_bf16(Abf + (size_t)mr * 256 + quad * 8, a[c]);
  }

#pragma unroll 1
  for (int tt = 0; tt < 4; ++tt) {
    const int t = tbase + tt;            // 16-wide tile id (val: 0..15, oa: 0..23)
    const int n = t * 16 + lo;
    const unsigned short* bt = Bt + (size_t)n * 256 + quad * 8;
    short8 b[8];
#pragma unroll
    for (int s = 0; s < 8; ++s) b[s] = *reinterpret_cast<const short8*>(bt + s * 32);
    f32x4 acc[4];
#pragma unroll
    for (int c = 0; c < 4; ++c) acc[c] = (f32x4){0.f, 0.f, 0.f, 0.f};
#pragma unroll
    for (int s = 0; s < 8; ++s)
#pragma unroll
      for (int c = 0; c < 4; ++c)
        acc[c] = __builtin_amdgcn_mfma_f32_16x16x32_bf16(a[c][s], b[s], acc[c], 0, 0, 0);

    if (isval) {
      const float bias = bv[n];
      const int h = n >> 5, d = n & 31;
#pragma unroll
      for (int c = 0; c < 4; ++c)
#pragma unroll
        for (int r = 0; r < 4; ++r) {
          const int m = m0 + c * 16 + quad * 4 + r;
          if (m < M) {
            const int bb = m / LV, i = m - bb * LV;
            val[(((size_t)(bb * NH + h)) * LV + i) * D + d] =
                (unsigned short)bf16r(acc[c][r] + bias);
          }
        }
    } else if (t < 16) {
      const int xy = n & 1, l = (n >> 3) & 3;
      const float sz = (l == 0) ? 100.f : (l == 1) ? 50.f : (l == 2) ? 25.f : 13.f;
      const float bias = boff[n];
#pragma unroll
      for (int c = 0; c < 4; ++c)
#pragma unroll
        for (int r = 0; r < 4; ++r) {
          const int m = m0 + c * 16 + quad * 4 + r;
          if (m < M) {
            float rv = rp[(size_t)m * 8 + l * 2 + xy];
            rv = fminf(fmaxf(rv, 1e-5f), 1.f - 1e-5f);
            loc[(size_t)m * 256 + n] = rv + (acc[c][r] + bias) / sz;
          }
        }
    } else {
      const int n2 = (t - 16) * 16 + lo;   // head*16 + col
      const float bias = battn[n2];
#pragma unroll
      for (int c = 0; c < 4; ++c)
#pragma unroll
        for (int r = 0; r < 4; ++r) {
          float v = acc[c][r] + bias;
          float mx = v;
#pragma unroll
          for (int msk = 8; msk >= 1; msk >>= 1) mx = fmaxf(mx, __shfl_xor(mx, msk, 64));
          const float e = __expf(v - mx);
          float s = e;
#pragma unroll
          for (int msk = 8; msk >= 1; msk >>= 1) s += __shfl_xor(s, msk, 64);
          const int m = m0 + c * 16 + quad * 4 + r;
          if (m < M) attn[(size_t)m * 128 + n2] = e / s;
        }
    }
  }
}

// ---------------------------------------------------------------------------
// GEMM 3: out = tmp @ Wo + bo + query, stored (LQ, B, C). tmp bf16. 4-chain.
// ---------------------------------------------------------------------------
__global__ __launch_bounds__(64) void k_gemm_out(
    const unsigned short* __restrict__ tmp, const float* __restrict__ query,
    const unsigned short* __restrict__ Bt, const float* __restrict__ bo,
    float* __restrict__ out) {
  const int lane = threadIdx.x, quad = lane >> 4, lo = lane & 15;
  const int m0 = blockIdx.x * 64;
  const int n0 = blockIdx.y * 64;
  short8 a[4][8];
#pragma unroll
  for (int c = 0; c < 4; ++c) {
    const int mr = min(m0 + c * 16 + lo, M - 1);
    load_a_bf16(tmp + (size_t)mr * 256 + quad * 8, a[c]);
  }
#pragma unroll 1
  for (int tt = 0; tt < 4; ++tt) {
    const int n = n0 + tt * 16 + lo;
    const unsigned short* bt = Bt + (size_t)n * 256 + quad * 8;
    short8 b[8];
#pragma unroll
    for (int s = 0; s < 8; ++s) b[s] = *reinterpret_cast<const short8*>(bt + s * 32);
    f32x4 acc[4];
#pragma unroll
    for (int c = 0; c < 4; ++c) acc[c] = (f32x4){0.f, 0.f, 0.f, 0.f};
#pragma unroll
    for (int s = 0; s < 8; ++s)
#pragma unroll
      for (int c = 0; c < 4; ++c)
        acc[c] = __builtin_amdgcn_mfma_f32_16x16x32_bf16(a[c][s], b[s], acc[c], 0, 0, 0);
    const float bias = bo[n];
#pragma unroll
    for (int c = 0; c < 4; ++c)
#pragma unroll
      for (int r = 0; r < 4; ++r) {
        const int m = m0 + c * 16 + quad * 4 + r;
        if (m < M) {
          const int bb = m / LQ, q = m - bb * LQ;
          const size_t o = ((size_t)(q * B + bb)) * C + n;
          out[o] = acc[c][r] + bias + query[o];
        }
      }
  }
}

// ---------------------------------------------------------------------------
// Bilinear sampling + attention weighting. VGPR=32 -> allow 8 waves/SIMD
// (latency/concurrency-bound: more resident waves = more outstanding misses).
// ---------------------------------------------------------------------------
__global__ __launch_bounds__(256, 8) void k_sample(
    const unsigned short* __restrict__ val, const float* __restrict__ loc,
    const float* __restrict__ attn, unsigned short* __restrict__ tmp) {
  constexpr int QPB = 8;
  const int mblk = blockIdx.x * QPB;
  const int t = threadIdx.x;
  __shared__ float sloc[QPB * 8 * 33];    // [q][h][33]
  __shared__ float sattn[QPB * 8 * 17];   // [q][h][17]
  for (int i = t; i < QPB * 256; i += 256) {
    int mq = mblk + (i >> 8); if (mq >= M) mq = M - 1;
    const int j = i & 255;
    sloc[(((i >> 8) << 3) + (j >> 5)) * 33 + (j & 31)] = loc[(size_t)mq * 256 + j];
  }
  for (int i = t; i < QPB * 128; i += 256) {
    int mq = mblk + (i >> 7); if (mq >= M) mq = M - 1;
    const int j = i & 127;
    sattn[(((i >> 7) << 3) + (j >> 4)) * 17 + (j & 15)] = attn[(size_t)mq * 128 + j];
  }
  __syncthreads();

  const int g = t >> 5, s = t & 31, h = s >> 2, c8 = s & 3;
  const int m = mblk + g;
  const int mc = (m < M) ? m : M - 1;
  const int b = mc / LQ;
  const unsigned short* vhead = val + ((size_t)(b * NH + h) * LV) * D + c8 * 8;
  const float* ql = sloc + (g * 8 + h) * 33;
  const float* qa = sattn + (g * 8 + h) * 17;

  float acc[8] = {0.f, 0.f, 0.f, 0.f, 0.f, 0.f, 0.f, 0.f};
#pragma unroll 1
  for (int l = 0; l < L; ++l) {
    const int Wl = SZ[l];
    const float Wlf = (float)Wl;
    const unsigned short* vlev = vhead + (size_t)START[l] * D;
#pragma unroll 2
    for (int p = 0; p < P; ++p) {
      const float x = ql[l * 8 + p * 2]     * Wlf - 0.5f;
      const float y = ql[l * 8 + p * 2 + 1] * Wlf - 0.5f;
      const float aw = qa[l * 4 + p];
      const float x0f = floorf(x), y0f = floorf(y);
      const float wx = x - x0f, wy = y - y0f;
      const int x0 = (int)x0f, y0 = (int)y0f;
      const float wy1 = wy * aw, wy0 = aw - wy1;  // aw*(1-wy)
      const float wx1 = wx, wx0 = 1.f - wx;
#pragma unroll
      for (int dy = 0; dy < 2; ++dy) {
#pragma unroll
        for (int dx = 0; dx < 2; ++dx) {
          const int yi = y0 + dy, xi = x0 + dx;
          const bool ok = (xi >= 0) & (xi < Wl) & (yi >= 0) & (yi < Wl);
          const int yc = min(max(yi, 0), Wl - 1);
          const int xc = min(max(xi, 0), Wl - 1);
          const float w = ok ? (dy ? wy1 : wy0) * (dx ? wx1 : wx0) : 0.f;
          const uint4 raw = *reinterpret_cast<const uint4*>(vlev + (yc * Wl + xc) * D);
          acc[0] = fmaf(w, __uint_as_float(raw.x << 16),          acc[0]);
          acc[1] = fmaf(w, __uint_as_float(raw.x & 0xffff0000u),  acc[1]);
          acc[2] = fmaf(w, __uint_as_float(raw.y << 16),          acc[2]);
          acc[3] = fmaf(w, __uint_as_float(raw.y & 0xffff0000u),  acc[3]);
          acc[4] = fmaf(w, __uint_as_float(raw.z << 16),          acc[4]);
          acc[5] = fmaf(w, __uint_as_float(raw.z & 0xffff0000u),  acc[5]);
          acc[6] = fmaf(w, __uint_as_float(raw.w << 16),          acc[6]);
          acc[7] = fmaf(w, __uint_as_float(raw.w & 0xffff0000u),  acc[7]);
        }
      }
    }
  }
  if (m < M) {
    short8 o;
#pragma unroll
    for (int j = 0; j < 8; ++j) o[j] = bf16r(acc[j]);
    *reinterpret_cast<short8*>(tmp + (size_t)m * 256 + h * 32 + c8 * 8) = o;
  }
}

}  // namespace

extern "C" void kernel_launch(void* const* d_in, const int* in_sizes, int n_in,
                              void* d_out, int out_size, void* d_ws, size_t ws_size,
                              hipStream_t stream) {
  const float* query = (const float*)d_in[0];
  const float* rp    = (const float*)d_in[1];
  const float* value = (const float*)d_in[2];
  const float* Wv    = (const float*)d_in[5];
  const float* bv    = (const float*)d_in[6];
  const float* Woff  = (const float*)d_in[7];
  const float* boff  = (const float*)d_in[8];
  const float* Wattn = (const float*)d_in[9];
  const float* battn = (const float*)d_in[10];
  const float* Wo    = (const float*)d_in[11];
  const float* bo    = (const float*)d_in[12];
  float* out = (float*)d_out;

  unsigned short* Btv  = (unsigned short*)d_ws;        // 256*256
  unsigned short* Btoa = Btv + 256 * 256;              // 384*256
  unsigned short* Bto  = Btoa + 384 * 256;             // 256*256
  unsigned short* qbf  = Bto + 256 * 256;              // M*256 bf16
  unsigned short* vbf  = qbf + (size_t)M * 256;        // M*256 bf16
  unsigned short* val  = vbf + (size_t)M * 256;        // M*256 bf16
  float* loc  = (float*)(val + (size_t)M * 256);       // M*256 f32
  float* attn = loc + (size_t)M * 256;                 // M*128 f32
  unsigned short* tmp = vbf;   // alias: vbf consumed by k_gemm12 before k_sample

  const int mtiles64 = (M + 63) / 64;                  // 416
  const int sample_blocks = (M + 7) / 8;               // 3324

  k_pre<<<CVT_BLOCKS + 224, 256, 0, stream>>>(query, value, Wv, Woff, Wattn, Wo,
                                              qbf, vbf, Btv, Btoa, Bto);
  k_gemm12<<<dim3(mtiles64, 10), 64, 0, stream>>>(qbf, vbf, rp, Btv, Btoa,
                                                  bv, boff, battn, val, loc, attn);
  k_sample<<<sample_blocks, 256, 0, stream>>>(val, loc, attn, tmp);
  k_gemm_out<<<dim3(mtiles64, 4), 64, 0, stream>>>(tmp, query, Bto, bo, out);
}

// Round 7
// 262.984 us; speedup vs baseline: 1.1884x; 1.1884x over previous
//
#include <hip/hip_runtime.h>
#include <math.h>

namespace {

typedef __attribute__((ext_vector_type(8))) short short8;
typedef __attribute__((ext_vector_type(4))) float f32x4;

constexpr int B  = 2;
constexpr int C  = 256;
constexpr int NH = 8;
constexpr int L  = 4;
constexpr int P  = 4;
constexpr int D  = 32;
constexpr int LV = 13294;
constexpr int LQ = 13294;
constexpr int M  = B * LQ;      // 26588 rows for all GEMMs

constexpr int SZ[4]    = {100, 50, 25, 13};
constexpr int START[4] = {0, 10000, 12500, 13125};

constexpr int CVT_BLOCKS = (2 * M) / 4;   // 13294 (exact: 4 rows/block)
constexpr int RS = 264;                   // LDS B row stride (shorts): 528 B, 16B-aligned, breaks bank aliasing

__device__ inline short bf16r(float f) {    // RTNE f32 -> bf16
  unsigned u = __float_as_uint(f);
  u += 0x7fff + ((u >> 16) & 1);
  return (short)(u >> 16);
}

__device__ inline void load_a_bf16(const unsigned short* __restrict__ arow, short8 a[8]) {
#pragma unroll
  for (int s = 0; s < 8; ++s)
    a[s] = *reinterpret_cast<const short8*>(arow + s * 32);
}

// ---------------------------------------------------------------------------
// k_pre: fused input convert (query/value f32 -> bf16 [m][256]) + weight
// transpose/convert (W[k][n] -> Bt[n][k] bf16).
// ---------------------------------------------------------------------------
__global__ __launch_bounds__(256) void k_pre(
    const float* __restrict__ query, const float* __restrict__ value,
    const float* __restrict__ Wv, const float* __restrict__ Woff,
    const float* __restrict__ Wattn, const float* __restrict__ Wo,
    unsigned short* __restrict__ qbf, unsigned short* __restrict__ vbf,
    unsigned short* __restrict__ Btv, unsigned short* __restrict__ Btoa,
    unsigned short* __restrict__ Bto) {
  __shared__ float tile[32][33];
  if (blockIdx.x < CVT_BLOCKS) {
    const int gid = blockIdx.x * 256 + threadIdx.x;
    const int rid = gid >> 6;              // row id over 2*M
    if (rid >= 2 * M) return;
    const int c4 = (gid & 63) * 4;
    const int tensor = (rid >= M) ? 1 : 0;
    const int m = tensor ? rid - M : rid;
    const int b = m / LQ, i = m - b * LQ;
    const float* src = (tensor ? value : query) + ((size_t)(i * B + b)) * C + c4;
    const f32x4 f = *reinterpret_cast<const f32x4*>(src);
    unsigned short* dst = (tensor ? vbf : qbf) + (size_t)m * C + c4;
    uint2 o;
    o.x = (unsigned)(unsigned short)bf16r(f[0]) | ((unsigned)(unsigned short)bf16r(f[1]) << 16);
    o.y = (unsigned)(unsigned short)bf16r(f[2]) | ((unsigned)(unsigned short)bf16r(f[3]) << 16);
    *reinterpret_cast<uint2*>(dst) = o;
    return;
  }
  const int blk = blockIdx.x - CVT_BLOCKS;
  const float* src; unsigned short* dst; int N, local;
  if (blk < 64)       { src = Wv;    dst = Btv;              N = 256; local = blk; }
  else if (blk < 128) { src = Woff;  dst = Btoa;             N = 256; local = blk - 64; }
  else if (blk < 160) { src = Wattn; dst = Btoa + 256 * 256; N = 128; local = blk - 128; }
  else                { src = Wo;    dst = Bto;              N = 256; local = blk - 160; }
  const int ntiles = N >> 5;
  const int kt = local / ntiles, nt = local - kt * ntiles;
  const int k0 = kt << 5, n0 = nt << 5;
  const int tx = threadIdx.x & 31, ty = threadIdx.x >> 5;
#pragma unroll
  for (int r = 0; r < 4; ++r) {
    const int kk = ty + r * 8;
    tile[kk][tx] = src[(size_t)(k0 + kk) * N + n0 + tx];
  }
  __syncthreads();
#pragma unroll
  for (int r = 0; r < 4; ++r) {
    const int nn = ty + r * 8;
    dst[(size_t)(n0 + nn) * 256 + k0 + tx] = (unsigned short)bf16r(tile[tx][nn]);
  }
}

// ---------------------------------------------------------------------------
// k_gemm12: merged GEMM 1 (val-proj) + GEMM 2 (offsets+attn).
// 256-thr / 4-wave blocks, tile 128(M) x 64(N). B-tile staged once in LDS
// (padded rows); each wave: 32 M-rows (2 chains, A in regs) x 4 N-tiles.
// blockIdx.y: 0..3 -> val-proj N-split; 4..9 -> offattn N-split.
// ---------------------------------------------------------------------------
__global__ __launch_bounds__(256) void k_gemm12(
    const unsigned short* __restrict__ qbf, const unsigned short* __restrict__ vbf,
    const float* __restrict__ rp,
    const unsigned short* __restrict__ Btv, const unsigned short* __restrict__ Btoa,
    const float* __restrict__ bv, const float* __restrict__ boff,
    const float* __restrict__ battn,
    unsigned short* __restrict__ val, float* __restrict__ loc,
    float* __restrict__ attn) {
  __shared__ unsigned short sB[64 * RS];    // 33 KB
  const int tid = threadIdx.x;
  const int wave = tid >> 6, lane = tid & 63, quad = lane >> 4, lo = lane & 15;
  const int y = blockIdx.y;
  const bool isval = (y < 4);
  const unsigned short* Abf = isval ? vbf : qbf;
  const unsigned short* Bt  = isval ? Btv : Btoa;
  const int n0 = isval ? y * 64 : (y - 4) * 64;   // col base in this weight
  const int m0 = blockIdx.x * 128;

  // Stage B: 64 rows x 512 B = 2048 uint4 chunks, 8 per thread, coalesced.
#pragma unroll
  for (int i = 0; i < 8; ++i) {
    const int cid = i * 256 + tid;
    const int row = cid >> 5, cc = cid & 31;
    const uint4 v = *reinterpret_cast<const uint4*>(Bt + (((size_t)(n0 + row)) << 8) + cc * 8);
    *reinterpret_cast<uint4*>(&sB[row * RS + cc * 8]) = v;
  }

  // A: 2 chains x 8 ksteps in registers.
  const int mrow = m0 + wave * 32;
  short8 a[2][8];
#pragma unroll
  for (int c = 0; c < 2; ++c) {
    const int mr = min(mrow + c * 16 + lo, M - 1);
    load_a_bf16(Abf + (size_t)mr * 256 + quad * 8, a[c]);
  }
  __syncthreads();

#pragma unroll 1
  for (int tt = 0; tt < 4; ++tt) {
    const unsigned short* bsrc = &sB[(tt * 16 + lo) * RS + quad * 8];
    short8 b[8];
#pragma unroll
    for (int s = 0; s < 8; ++s)
      b[s] = *reinterpret_cast<const short8*>(bsrc + s * 32);
    f32x4 acc[2];
    acc[0] = (f32x4){0.f, 0.f, 0.f, 0.f};
    acc[1] = (f32x4){0.f, 0.f, 0.f, 0.f};
#pragma unroll
    for (int s = 0; s < 8; ++s) {
      acc[0] = __builtin_amdgcn_mfma_f32_16x16x32_bf16(a[0][s], b[s], acc[0], 0, 0, 0);
      acc[1] = __builtin_amdgcn_mfma_f32_16x16x32_bf16(a[1][s], b[s], acc[1], 0, 0, 0);
    }

    const int n = n0 + tt * 16 + lo;     // global col in this weight
    if (isval) {
      const float bias = bv[n];
      const int h = n >> 5, d = n & 31;
#pragma unroll
      for (int c = 0; c < 2; ++c)
#pragma unroll
        for (int r = 0; r < 4; ++r) {
          const int m = mrow + c * 16 + quad * 4 + r;
          if (m < M) {
            const int bb = m / LV, i = m - bb * LV;
            val[(((size_t)(bb * NH + h)) * LV + i) * D + d] =
                (unsigned short)bf16r(acc[c][r] + bias);
          }
        }
    } else if (n < 256) {
      const int xy = n & 1, l = (n >> 3) & 3;
      const float sz = (l == 0) ? 100.f : (l == 1) ? 50.f : (l == 2) ? 25.f : 13.f;
      const float bias = boff[n];
#pragma unroll
      for (int c = 0; c < 2; ++c)
#pragma unroll
        for (int r = 0; r < 4; ++r) {
          const int m = mrow + c * 16 + quad * 4 + r;
          if (m < M) {
            float rv = rp[(size_t)m * 8 + l * 2 + xy];
            rv = fminf(fmaxf(rv, 1e-5f), 1.f - 1e-5f);
            loc[(size_t)m * 256 + n] = rv + (acc[c][r] + bias) / sz;
          }
        }
    } else {
      const int n2 = n - 256;            // head*16 + col
      const float bias = battn[n2];
#pragma unroll
      for (int c = 0; c < 2; ++c)
#pragma unroll
        for (int r = 0; r < 4; ++r) {
          float v = acc[c][r] + bias;
          float mx = v;
#pragma unroll
          for (int msk = 8; msk >= 1; msk >>= 1) mx = fmaxf(mx, __shfl_xor(mx, msk, 64));
          const float e = __expf(v - mx);
          float s = e;
#pragma unroll
          for (int msk = 8; msk >= 1; msk >>= 1) s += __shfl_xor(s, msk, 64);
          const int m = mrow + c * 16 + quad * 4 + r;
          if (m < M) attn[(size_t)m * 128 + n2] = e / s;
        }
    }
  }
}

// ---------------------------------------------------------------------------
// GEMM 3: out = tmp @ Wo + bo + query (LQ,B,C). Same block structure.
// ---------------------------------------------------------------------------
__global__ __launch_bounds__(256) void k_gemm3(
    const unsigned short* __restrict__ tmp, const float* __restrict__ query,
    const unsigned short* __restrict__ Bt, const float* __restrict__ bo,
    float* __restrict__ out) {
  __shared__ unsigned short sB[64 * RS];
  const int tid = threadIdx.x;
  const int wave = tid >> 6, lane = tid & 63, quad = lane >> 4, lo = lane & 15;
  const int n0 = blockIdx.y * 64;
  const int m0 = blockIdx.x * 128;

#pragma unroll
  for (int i = 0; i < 8; ++i) {
    const int cid = i * 256 + tid;
    const int row = cid >> 5, cc = cid & 31;
    const uint4 v = *reinterpret_cast<const uint4*>(Bt + (((size_t)(n0 + row)) << 8) + cc * 8);
    *reinterpret_cast<uint4*>(&sB[row * RS + cc * 8]) = v;
  }
  const int mrow = m0 + wave * 32;
  short8 a[2][8];
#pragma unroll
  for (int c = 0; c < 2; ++c) {
    const int mr = min(mrow + c * 16 + lo, M - 1);
    load_a_bf16(tmp + (size_t)mr * 256 + quad * 8, a[c]);
  }
  __syncthreads();

#pragma unroll 1
  for (int tt = 0; tt < 4; ++tt) {
    const unsigned short* bsrc = &sB[(tt * 16 + lo) * RS + quad * 8];
    short8 b[8];
#pragma unroll
    for (int s = 0; s < 8; ++s)
      b[s] = *reinterpret_cast<const short8*>(bsrc + s * 32);
    f32x4 acc[2];
    acc[0] = (f32x4){0.f, 0.f, 0.f, 0.f};
    acc[1] = (f32x4){0.f, 0.f, 0.f, 0.f};
#pragma unroll
    for (int s = 0; s < 8; ++s) {
      acc[0] = __builtin_amdgcn_mfma_f32_16x16x32_bf16(a[0][s], b[s], acc[0], 0, 0, 0);
      acc[1] = __builtin_amdgcn_mfma_f32_16x16x32_bf16(a[1][s], b[s], acc[1], 0, 0, 0);
    }
    const int n = n0 + tt * 16 + lo;
    const float bias = bo[n];
#pragma unroll
    for (int c = 0; c < 2; ++c)
#pragma unroll
      for (int r = 0; r < 4; ++r) {
        const int m = mrow + c * 16 + quad * 4 + r;
        if (m < M) {
          const int bb = m / LQ, q = m - bb * LQ;
          const size_t o = ((size_t)(q * B + bb)) * C + n;
          out[o] = acc[c][r] + bias + query[o];
        }
      }
  }
}

// ---------------------------------------------------------------------------
// Bilinear sampling + attention weighting (R4/R5 proven version, 75.7 us).
// ---------------------------------------------------------------------------
__global__ __launch_bounds__(256, 4) void k_sample(
    const unsigned short* __restrict__ val, const float* __restrict__ loc,
    const float* __restrict__ attn, unsigned short* __restrict__ tmp) {
  constexpr int QPB = 8;
  const int mblk = blockIdx.x * QPB;
  const int t = threadIdx.x;
  __shared__ float sloc[QPB * 8 * 33];    // [q][h][33]
  __shared__ float sattn[QPB * 8 * 17];   // [q][h][17]
  for (int i = t; i < QPB * 256; i += 256) {
    int mq = mblk + (i >> 8); if (mq >= M) mq = M - 1;
    const int j = i & 255;
    sloc[(((i >> 8) << 3) + (j >> 5)) * 33 + (j & 31)] = loc[(size_t)mq * 256 + j];
  }
  for (int i = t; i < QPB * 128; i += 256) {
    int mq = mblk + (i >> 7); if (mq >= M) mq = M - 1;
    const int j = i & 127;
    sattn[(((i >> 7) << 3) + (j >> 4)) * 17 + (j & 15)] = attn[(size_t)mq * 128 + j];
  }
  __syncthreads();

  const int g = t >> 5, s = t & 31, h = s >> 2, c8 = s & 3;
  const int m = mblk + g;
  const int mc = (m < M) ? m : M - 1;
  const int b = mc / LQ;
  const unsigned short* vhead = val + ((size_t)(b * NH + h) * LV) * D + c8 * 8;
  const float* ql = sloc + (g * 8 + h) * 33;
  const float* qa = sattn + (g * 8 + h) * 17;

  float acc[8] = {0.f, 0.f, 0.f, 0.f, 0.f, 0.f, 0.f, 0.f};
#pragma unroll 1
  for (int l = 0; l < L; ++l) {
    const int Wl = SZ[l];
    const float Wlf = (float)Wl;
    const unsigned short* vlev = vhead + (size_t)START[l] * D;
#pragma unroll 2
    for (int p = 0; p < P; ++p) {
      const float x = ql[l * 8 + p * 2]     * Wlf - 0.5f;
      const float y = ql[l * 8 + p * 2 + 1] * Wlf - 0.5f;
      const float aw = qa[l * 4 + p];
      const float x0f = floorf(x), y0f = floorf(y);
      const float wx = x - x0f, wy = y - y0f;
      const int x0 = (int)x0f, y0 = (int)y0f;
      const float wy1 = wy * aw, wy0 = aw - wy1;  // aw*(1-wy)
      const float wx1 = wx, wx0 = 1.f - wx;
#pragma unroll
      for (int dy = 0; dy < 2; ++dy) {
#pragma unroll
        for (int dx = 0; dx < 2; ++dx) {
          const int yi = y0 + dy, xi = x0 + dx;
          const bool ok = (xi >= 0) & (xi < Wl) & (yi >= 0) & (yi < Wl);
          const int yc = min(max(yi, 0), Wl - 1);
          const int xc = min(max(xi, 0), Wl - 1);
          const float w = ok ? (dy ? wy1 : wy0) * (dx ? wx1 : wx0) : 0.f;
          const uint4 raw = *reinterpret_cast<const uint4*>(vlev + (yc * Wl + xc) * D);
          acc[0] = fmaf(w, __uint_as_float(raw.x << 16),          acc[0]);
          acc[1] = fmaf(w, __uint_as_float(raw.x & 0xffff0000u),  acc[1]);
          acc[2] = fmaf(w, __uint_as_float(raw.y << 16),          acc[2]);
          acc[3] = fmaf(w, __uint_as_float(raw.y & 0xffff0000u),  acc[3]);
          acc[4] = fmaf(w, __uint_as_float(raw.z << 16),          acc[4]);
          acc[5] = fmaf(w, __uint_as_float(raw.z & 0xffff0000u),  acc[5]);
          acc[6] = fmaf(w, __uint_as_float(raw.w << 16),          acc[6]);
          acc[7] = fmaf(w, __uint_as_float(raw.w & 0xffff0000u),  acc[7]);
        }
      }
    }
  }
  if (m < M) {
    short8 o;
#pragma unroll
    for (int j = 0; j < 8; ++j) o[j] = bf16r(acc[j]);
    *reinterpret_cast<short8*>(tmp + (size_t)m * 256 + h * 32 + c8 * 8) = o;
  }
}

}  // namespace

extern "C" void kernel_launch(void* const* d_in, const int* in_sizes, int n_in,
                              void* d_out, int out_size, void* d_ws, size_t ws_size,
                              hipStream_t stream) {
  const float* query = (const float*)d_in[0];
  const float* rp    = (const float*)d_in[1];
  const float* value = (const float*)d_in[2];
  const float* Wv    = (const float*)d_in[5];
  const float* bv    = (const float*)d_in[6];
  const float* Woff  = (const float*)d_in[7];
  const float* boff  = (const float*)d_in[8];
  const float* Wattn = (const float*)d_in[9];
  const float* battn = (const float*)d_in[10];
  const float* Wo    = (const float*)d_in[11];
  const float* bo    = (const float*)d_in[12];
  float* out = (float*)d_out;

  unsigned short* Btv  = (unsigned short*)d_ws;        // 256*256
  unsigned short* Btoa = Btv + 256 * 256;              // 384*256
  unsigned short* Bto  = Btoa + 384 * 256;             // 256*256
  unsigned short* qbf  = Bto + 256 * 256;              // M*256 bf16
  unsigned short* vbf  = qbf + (size_t)M * 256;        // M*256 bf16
  unsigned short* val  = vbf + (size_t)M * 256;        // M*256 bf16
  float* loc  = (float*)(val + (size_t)M * 256);       // M*256 f32
  float* attn = loc + (size_t)M * 256;                 // M*128 f32
  unsigned short* tmp = vbf;   // alias: vbf consumed by k_gemm12 before k_sample

  const int mtiles128 = (M + 127) / 128;               // 208
  const int sample_blocks = (M + 7) / 8;               // 3324

  k_pre<<<CVT_BLOCKS + 224, 256, 0, stream>>>(query, value, Wv, Woff, Wattn, Wo,
                                              qbf, vbf, Btv, Btoa, Bto);
  k_gemm12<<<dim3(mtiles128, 10), 256, 0, stream>>>(qbf, vbf, rp, Btv, Btoa,
                                                    bv, boff, battn, val, loc, attn);
  k_sample<<<sample_blocks, 256, 0, stream>>>(val, loc, attn, tmp);
  k_gemm3<<<dim3(mtiles128, 4), 256, 0, stream>>>(tmp, query, Bto, bo, out);
}

// Round 8
// 238.032 us; speedup vs baseline: 1.3130x; 1.1048x over previous
//
#include <hip/hip_runtime.h>
#include <math.h>

namespace {

typedef __attribute__((ext_vector_type(8))) short short8;
typedef __attribute__((ext_vector_type(4))) float f32x4;

constexpr int B  = 2;
constexpr int C  = 256;
constexpr int NH = 8;
constexpr int L  = 4;
constexpr int P  = 4;
constexpr int D  = 32;
constexpr int LV = 13294;
constexpr int LQ = 13294;
constexpr int M  = B * LQ;      // 26588 rows for all GEMMs

constexpr int SZ[4]    = {100, 50, 25, 13};
constexpr int START[4] = {0, 10000, 12500, 13125};

constexpr int CVT_BLOCKS = (2 * M) / 4;   // 13294 (exact: 4 rows/block)
constexpr int RS = 264;                   // LDS B row stride (shorts)

__device__ inline short bf16r(float f) {    // RTNE f32 -> bf16
  unsigned u = __float_as_uint(f);
  u += 0x7fff + ((u >> 16) & 1);
  return (short)(u >> 16);
}

__device__ inline void load_a_bf16(const unsigned short* __restrict__ arow, short8 a[8]) {
#pragma unroll
  for (int s = 0; s < 8; ++s)
    a[s] = *reinterpret_cast<const short8*>(arow + s * 32);
}

// ---------------------------------------------------------------------------
// k_pre: fused input convert (query/value f32 -> bf16 [m][256]) + weight
// transpose/convert (W[k][n] -> Bt[n][k] bf16).
// ---------------------------------------------------------------------------
__global__ __launch_bounds__(256) void k_pre(
    const float* __restrict__ query, const float* __restrict__ value,
    const float* __restrict__ Wv, const float* __restrict__ Woff,
    const float* __restrict__ Wattn, const float* __restrict__ Wo,
    unsigned short* __restrict__ qbf, unsigned short* __restrict__ vbf,
    unsigned short* __restrict__ Btv, unsigned short* __restrict__ Btoa,
    unsigned short* __restrict__ Bto) {
  __shared__ float tile[32][33];
  if (blockIdx.x < CVT_BLOCKS) {
    const int gid = blockIdx.x * 256 + threadIdx.x;
    const int rid = gid >> 6;              // row id over 2*M
    if (rid >= 2 * M) return;
    const int c4 = (gid & 63) * 4;
    const int tensor = (rid >= M) ? 1 : 0;
    const int m = tensor ? rid - M : rid;
    const int b = m / LQ, i = m - b * LQ;
    const float* src = (tensor ? value : query) + ((size_t)(i * B + b)) * C + c4;
    const f32x4 f = *reinterpret_cast<const f32x4*>(src);
    unsigned short* dst = (tensor ? vbf : qbf) + (size_t)m * C + c4;
    uint2 o;
    o.x = (unsigned)(unsigned short)bf16r(f[0]) | ((unsigned)(unsigned short)bf16r(f[1]) << 16);
    o.y = (unsigned)(unsigned short)bf16r(f[2]) | ((unsigned)(unsigned short)bf16r(f[3]) << 16);
    *reinterpret_cast<uint2*>(dst) = o;
    return;
  }
  const int blk = blockIdx.x - CVT_BLOCKS;
  const float* src; unsigned short* dst; int N, local;
  if (blk < 64)       { src = Wv;    dst = Btv;              N = 256; local = blk; }
  else if (blk < 128) { src = Woff;  dst = Btoa;             N = 256; local = blk - 64; }
  else if (blk < 160) { src = Wattn; dst = Btoa + 256 * 256; N = 128; local = blk - 128; }
  else                { src = Wo;    dst = Bto;              N = 256; local = blk - 160; }
  const int ntiles = N >> 5;
  const int kt = local / ntiles, nt = local - kt * ntiles;
  const int k0 = kt << 5, n0 = nt << 5;
  const int tx = threadIdx.x & 31, ty = threadIdx.x >> 5;
#pragma unroll
  for (int r = 0; r < 4; ++r) {
    const int kk = ty + r * 8;
    tile[kk][tx] = src[(size_t)(k0 + kk) * N + n0 + tx];
  }
  __syncthreads();
#pragma unroll
  for (int r = 0; r < 4; ++r) {
    const int nn = ty + r * 8;
    dst[(size_t)(n0 + nn) * 256 + k0 + tx] = (unsigned short)bf16r(tile[tx][nn]);
  }
}

// ---------------------------------------------------------------------------
// GEMM core change (R8): operand-swapped MFMA — mfma(b, a, acc) computes
// (A.B)^T, so each lane holds col m = lane&15 (fixed) and rows
// n = tilebase + quad*4 + r, i.e. 4 CONSECUTIVE output columns -> float4 /
// ushort4 epilogue stores. Blocks: 128 M x 128 N, B-tile (128x256 bf16,
// padded) staged once in LDS, 4 waves x (32 M-rows, 2 chains) x 8 N-tiles.
// ---------------------------------------------------------------------------

// k_gemm12: blockIdx.y 0..1 -> val-proj (N=256), 2..4 -> offattn (N=384).
__global__ __launch_bounds__(256, 2) void k_gemm12(
    const unsigned short* __restrict__ qbf, const unsigned short* __restrict__ vbf,
    const float* __restrict__ rp,
    const unsigned short* __restrict__ Btv, const unsigned short* __restrict__ Btoa,
    const float* __restrict__ bv, const float* __restrict__ boff,
    const float* __restrict__ battn,
    unsigned short* __restrict__ val, float* __restrict__ loc,
    float* __restrict__ attn) {
  __shared__ unsigned short sB[128 * RS];   // ~67.6 KB
  const int tid = threadIdx.x;
  const int wave = tid >> 6, lane = tid & 63, quad = lane >> 4, lo = lane & 15;
  const int y = blockIdx.y;
  const bool isval = (y < 2);
  const unsigned short* Abf = isval ? vbf : qbf;
  const unsigned short* Bt  = isval ? Btv : Btoa;
  const int n0 = isval ? y * 128 : (y - 2) * 128;
  const int m0 = blockIdx.x * 128;

  // Stage B: 128 rows x 512 B = 4096 uint4 chunks, 16/thread, coalesced.
#pragma unroll
  for (int i = 0; i < 16; ++i) {
    const int cid = i * 256 + tid;
    const int row = cid >> 5, cc = cid & 31;
    const uint4 v = *reinterpret_cast<const uint4*>(Bt + (((size_t)(n0 + row)) << 8) + cc * 8);
    *reinterpret_cast<uint4*>(&sB[row * RS + cc * 8]) = v;
  }

  const int mrow = m0 + wave * 32;
  short8 a[2][8];
#pragma unroll
  for (int c = 0; c < 2; ++c) {
    const int mr = min(mrow + c * 16 + lo, M - 1);
    load_a_bf16(Abf + (size_t)mr * 256 + quad * 8, a[c]);
  }
  __syncthreads();

#pragma unroll 1
  for (int tt = 0; tt < 8; ++tt) {
    const unsigned short* bsrc = &sB[(tt * 16 + lo) * RS + quad * 8];
    short8 b[8];
#pragma unroll
    for (int s = 0; s < 8; ++s)
      b[s] = *reinterpret_cast<const short8*>(bsrc + s * 32);
    f32x4 acc[2];
    acc[0] = (f32x4){0.f, 0.f, 0.f, 0.f};
    acc[1] = (f32x4){0.f, 0.f, 0.f, 0.f};
#pragma unroll
    for (int s = 0; s < 8; ++s) {
      acc[0] = __builtin_amdgcn_mfma_f32_16x16x32_bf16(b[s], a[0][s], acc[0], 0, 0, 0);
      acc[1] = __builtin_amdgcn_mfma_f32_16x16x32_bf16(b[s], a[1][s], acc[1], 0, 0, 0);
    }

    const int nb = n0 + tt * 16 + quad * 4;     // this lane's 4 consecutive cols
    if (isval) {
      const f32x4 bias4 = *reinterpret_cast<const f32x4*>(bv + nb);
      const int h = nb >> 5, d0 = nb & 31;
#pragma unroll
      for (int c = 0; c < 2; ++c) {
        const int m = mrow + c * 16 + lo;
        if (m < M) {
          const int bb = m / LV, i = m - bb * LV;
          ushort4 o;
          o.x = (unsigned short)bf16r(acc[c][0] + bias4[0]);
          o.y = (unsigned short)bf16r(acc[c][1] + bias4[1]);
          o.z = (unsigned short)bf16r(acc[c][2] + bias4[2]);
          o.w = (unsigned short)bf16r(acc[c][3] + bias4[3]);
          *reinterpret_cast<ushort4*>(
              val + (((size_t)(bb * NH + h)) * LV + i) * D + d0) = o;
        }
      }
    } else if (nb < 256) {
      const f32x4 bias4 = *reinterpret_cast<const f32x4*>(boff + nb);
      const int l = (nb >> 3) & 3;
      const float sz = (l == 0) ? 100.f : (l == 1) ? 50.f : (l == 2) ? 25.f : 13.f;
#pragma unroll
      for (int c = 0; c < 2; ++c) {
        const int m = mrow + c * 16 + lo;
        if (m < M) {
          const float2 rv2 = *reinterpret_cast<const float2*>(rp + (size_t)m * 8 + l * 2);
          const float rx = fminf(fmaxf(rv2.x, 1e-5f), 1.f - 1e-5f);
          const float ry = fminf(fmaxf(rv2.y, 1e-5f), 1.f - 1e-5f);
          f32x4 o;
          o[0] = rx + (acc[c][0] + bias4[0]) / sz;
          o[1] = ry + (acc[c][1] + bias4[1]) / sz;
          o[2] = rx + (acc[c][2] + bias4[2]) / sz;
          o[3] = ry + (acc[c][3] + bias4[3]) / sz;
          *reinterpret_cast<f32x4*>(loc + (size_t)m * 256 + nb) = o;
        }
      }
    } else {
      const int n2 = nb - 256;                  // head*16 + 4-aligned col
      const f32x4 bias4 = *reinterpret_cast<const f32x4*>(battn + n2);
#pragma unroll
      for (int c = 0; c < 2; ++c) {
        float v0 = acc[c][0] + bias4[0], v1 = acc[c][1] + bias4[1];
        float v2 = acc[c][2] + bias4[2], v3 = acc[c][3] + bias4[3];
        float mx = fmaxf(fmaxf(v0, v1), fmaxf(v2, v3));
        mx = fmaxf(mx, __shfl_xor(mx, 16, 64));
        mx = fmaxf(mx, __shfl_xor(mx, 32, 64));
        const float e0 = __expf(v0 - mx), e1 = __expf(v1 - mx);
        const float e2 = __expf(v2 - mx), e3 = __expf(v3 - mx);
        float s = e0 + e1 + e2 + e3;
        s += __shfl_xor(s, 16, 64);
        s += __shfl_xor(s, 32, 64);
        const float inv = 1.f / s;
        const int m = mrow + c * 16 + lo;
        if (m < M) {
          f32x4 o; o[0] = e0 * inv; o[1] = e1 * inv; o[2] = e2 * inv; o[3] = e3 * inv;
          *reinterpret_cast<f32x4*>(attn + (size_t)m * 128 + n2) = o;
        }
      }
    }
  }
}

// ---------------------------------------------------------------------------
// GEMM 3: out = tmp @ Wo + bo + query (LQ,B,C). Same swapped structure.
// ---------------------------------------------------------------------------
__global__ __launch_bounds__(256, 2) void k_gemm3(
    const unsigned short* __restrict__ tmp, const float* __restrict__ query,
    const unsigned short* __restrict__ Bt, const float* __restrict__ bo,
    float* __restrict__ out) {
  __shared__ unsigned short sB[128 * RS];
  const int tid = threadIdx.x;
  const int wave = tid >> 6, lane = tid & 63, quad = lane >> 4, lo = lane & 15;
  const int n0 = blockIdx.y * 128;
  const int m0 = blockIdx.x * 128;

#pragma unroll
  for (int i = 0; i < 16; ++i) {
    const int cid = i * 256 + tid;
    const int row = cid >> 5, cc = cid & 31;
    const uint4 v = *reinterpret_cast<const uint4*>(Bt + (((size_t)(n0 + row)) << 8) + cc * 8);
    *reinterpret_cast<uint4*>(&sB[row * RS + cc * 8]) = v;
  }
  const int mrow = m0 + wave * 32;
  short8 a[2][8];
#pragma unroll
  for (int c = 0; c < 2; ++c) {
    const int mr = min(mrow + c * 16 + lo, M - 1);
    load_a_bf16(tmp + (size_t)mr * 256 + quad * 8, a[c]);
  }
  __syncthreads();

#pragma unroll 1
  for (int tt = 0; tt < 8; ++tt) {
    const unsigned short* bsrc = &sB[(tt * 16 + lo) * RS + quad * 8];
    short8 b[8];
#pragma unroll
    for (int s = 0; s < 8; ++s)
      b[s] = *reinterpret_cast<const short8*>(bsrc + s * 32);
    f32x4 acc[2];
    acc[0] = (f32x4){0.f, 0.f, 0.f, 0.f};
    acc[1] = (f32x4){0.f, 0.f, 0.f, 0.f};
#pragma unroll
    for (int s = 0; s < 8; ++s) {
      acc[0] = __builtin_amdgcn_mfma_f32_16x16x32_bf16(b[s], a[0][s], acc[0], 0, 0, 0);
      acc[1] = __builtin_amdgcn_mfma_f32_16x16x32_bf16(b[s], a[1][s], acc[1], 0, 0, 0);
    }
    const int nb = n0 + tt * 16 + quad * 4;
    const f32x4 bias4 = *reinterpret_cast<const f32x4*>(bo + nb);
#pragma unroll
    for (int c = 0; c < 2; ++c) {
      const int m = mrow + c * 16 + lo;
      if (m < M) {
        const int bb = m / LQ, q = m - bb * LQ;
        const size_t o = ((size_t)(q * B + bb)) * C + nb;
        const f32x4 qv = *reinterpret_cast<const f32x4*>(query + o);
        f32x4 ov;
        ov[0] = acc[c][0] + bias4[0] + qv[0];
        ov[1] = acc[c][1] + bias4[1] + qv[1];
        ov[2] = acc[c][2] + bias4[2] + qv[2];
        ov[3] = acc[c][3] + bias4[3] + qv[3];
        *reinterpret_cast<f32x4*>(out + o) = ov;
      }
    }
  }
}

// ---------------------------------------------------------------------------
// Bilinear sampling + attention weighting (proven R4 version, ~77 us —
// at the VMEM instruction-issue floor).
// ---------------------------------------------------------------------------
__global__ __launch_bounds__(256, 4) void k_sample(
    const unsigned short* __restrict__ val, const float* __restrict__ loc,
    const float* __restrict__ attn, unsigned short* __restrict__ tmp) {
  constexpr int QPB = 8;
  const int mblk = blockIdx.x * QPB;
  const int t = threadIdx.x;
  __shared__ float sloc[QPB * 8 * 33];    // [q][h][33]
  __shared__ float sattn[QPB * 8 * 17];   // [q][h][17]
  for (int i = t; i < QPB * 256; i += 256) {
    int mq = mblk + (i >> 8); if (mq >= M) mq = M - 1;
    const int j = i & 255;
    sloc[(((i >> 8) << 3) + (j >> 5)) * 33 + (j & 31)] = loc[(size_t)mq * 256 + j];
  }
  for (int i = t; i < QPB * 128; i += 256) {
    int mq = mblk + (i >> 7); if (mq >= M) mq = M - 1;
    const int j = i & 127;
    sattn[(((i >> 7) << 3) + (j >> 4)) * 17 + (j & 15)] = attn[(size_t)mq * 128 + j];
  }
  __syncthreads();

  const int g = t >> 5, s = t & 31, h = s >> 2, c8 = s & 3;
  const int m = mblk + g;
  const int mc = (m < M) ? m : M - 1;
  const int b = mc / LQ;
  const unsigned short* vhead = val + ((size_t)(b * NH + h) * LV) * D + c8 * 8;
  const float* ql = sloc + (g * 8 + h) * 33;
  const float* qa = sattn + (g * 8 + h) * 17;

  float acc[8] = {0.f, 0.f, 0.f, 0.f, 0.f, 0.f, 0.f, 0.f};
#pragma unroll 1
  for (int l = 0; l < L; ++l) {
    const int Wl = SZ[l];
    const float Wlf = (float)Wl;
    const unsigned short* vlev = vhead + (size_t)START[l] * D;
#pragma unroll 2
    for (int p = 0; p < P; ++p) {
      const float x = ql[l * 8 + p * 2]     * Wlf - 0.5f;
      const float y = ql[l * 8 + p * 2 + 1] * Wlf - 0.5f;
      const float aw = qa[l * 4 + p];
      const float x0f = floorf(x), y0f = floorf(y);
      const float wx = x - x0f, wy = y - y0f;
      const int x0 = (int)x0f, y0 = (int)y0f;
      const float wy1 = wy * aw, wy0 = aw - wy1;  // aw*(1-wy)
      const float wx1 = wx, wx0 = 1.f - wx;
#pragma unroll
      for (int dy = 0; dy < 2; ++dy) {
#pragma unroll
        for (int dx = 0; dx < 2; ++dx) {
          const int yi = y0 + dy, xi = x0 + dx;
          const bool ok = (xi >= 0) & (xi < Wl) & (yi >= 0) & (yi < Wl);
          const int yc = min(max(yi, 0), Wl - 1);
          const int xc = min(max(xi, 0), Wl - 1);
          const float w = ok ? (dy ? wy1 : wy0) * (dx ? wx1 : wx0) : 0.f;
          const uint4 raw = *reinterpret_cast<const uint4*>(vlev + (yc * Wl + xc) * D);
          acc[0] = fmaf(w, __uint_as_float(raw.x << 16),          acc[0]);
          acc[1] = fmaf(w, __uint_as_float(raw.x & 0xffff0000u),  acc[1]);
          acc[2] = fmaf(w, __uint_as_float(raw.y << 16),          acc[2]);
          acc[3] = fmaf(w, __uint_as_float(raw.y & 0xffff0000u),  acc[3]);
          acc[4] = fmaf(w, __uint_as_float(raw.z << 16),          acc[4]);
          acc[5] = fmaf(w, __uint_as_float(raw.z & 0xffff0000u),  acc[5]);
          acc[6] = fmaf(w, __uint_as_float(raw.w << 16),          acc[6]);
          acc[7] = fmaf(w, __uint_as_float(raw.w & 0xffff0000u),  acc[7]);
        }
      }
    }
  }
  if (m < M) {
    short8 o;
#pragma unroll
    for (int j = 0; j < 8; ++j) o[j] = bf16r(acc[j]);
    *reinterpret_cast<short8*>(tmp + (size_t)m * 256 + h * 32 + c8 * 8) = o;
  }
}

}  // namespace

extern "C" void kernel_launch(void* const* d_in, const int* in_sizes, int n_in,
                              void* d_out, int out_size, void* d_ws, size_t ws_size,
                              hipStream_t stream) {
  const float* query = (const float*)d_in[0];
  const float* rp    = (const float*)d_in[1];
  const float* value = (const float*)d_in[2];
  const float* Wv    = (const float*)d_in[5];
  const float* bv    = (const float*)d_in[6];
  const float* Woff  = (const float*)d_in[7];
  const float* boff  = (const float*)d_in[8];
  const float* Wattn = (const float*)d_in[9];
  const float* battn = (const float*)d_in[10];
  const float* Wo    = (const float*)d_in[11];
  const float* bo    = (const float*)d_in[12];
  float* out = (float*)d_out;

  unsigned short* Btv  = (unsigned short*)d_ws;        // 256*256
  unsigned short* Btoa = Btv + 256 * 256;              // 384*256
  unsigned short* Bto  = Btoa + 384 * 256;             // 256*256
  unsigned short* qbf  = Bto + 256 * 256;              // M*256 bf16
  unsigned short* vbf  = qbf + (size_t)M * 256;        // M*256 bf16
  unsigned short* val  = vbf + (size_t)M * 256;        // M*256 bf16
  float* loc  = (float*)(val + (size_t)M * 256);       // M*256 f32
  float* attn = loc + (size_t)M * 256;                 // M*128 f32
  unsigned short* tmp = vbf;   // alias: vbf consumed by k_gemm12 before k_sample

  const int mtiles128 = (M + 127) / 128;               // 208
  const int sample_blocks = (M + 7) / 8;               // 3324

  k_pre<<<CVT_BLOCKS + 224, 256, 0, stream>>>(query, value, Wv, Woff, Wattn, Wo,
                                              qbf, vbf, Btv, Btoa, Bto);
  k_gemm12<<<dim3(mtiles128, 5), 256, 0, stream>>>(qbf, vbf, rp, Btv, Btoa,
                                                   bv, boff, battn, val, loc, attn);
  k_sample<<<sample_blocks, 256, 0, stream>>>(val, loc, attn, tmp);
  k_gemm3<<<dim3(mtiles128, 2), 256, 0, stream>>>(tmp, query, Bto, bo, out);
}